// Round 6
// baseline (574.703 us; speedup 1.0000x reference)
//
#include <hip/hip_runtime.h>
#include <hip/hip_bf16.h>

typedef unsigned short u16;
typedef __attribute__((ext_vector_type(8))) short short8;
typedef __attribute__((ext_vector_type(4))) short short4v;
typedef __attribute__((ext_vector_type(4))) float f32x4;

#define HEADS 20
#define HD 64
#define BB 8
#define SQ 4096
#define HDIM 1280
#define SKV 109
#define CDIM 768
#define SKV_PAD 128
#define SKV_T 112

#define SBAR() asm volatile("s_barrier" ::: "memory")

static __device__ __forceinline__ u16 f2bf(float x) {
  union { __hip_bfloat16 h; u16 u; } cv;
  cv.h = __float2bfloat16(x);
  return cv.u;
}

// async global->LDS, 16B per lane (dest = wave-uniform base + lane*16).
static __device__ __forceinline__ void gll16(const void* g, void* l) {
  __builtin_amdgcn_global_load_lds(
      (const __attribute__((address_space(1))) unsigned int*)g,
      (__attribute__((address_space(3))) unsigned int*)l, 16, 0, 0);
}

// inline-asm ds_read_b128: invisible to the compiler's auto-waitcnt pass, so
// no conservative vmcnt drain is inserted against outstanding LDS-DMA.
// Ordering is enforced manually: explicit lgkmcnt(0) + sched_barrier (rule #18).
static __device__ __forceinline__ short8 ldsr(unsigned addr) {
  short8 d;
  asm volatile("ds_read_b128 %0, %1" : "=v"(d) : "v"(addr));
  return d;
}

// ---- prep: out[n][k] = bf16(W[k][n] * scale)  (W is K x N row-major)
__global__ __launch_bounds__(256) void tcvt(const float* __restrict__ W,
                                            u16* __restrict__ out, int K, int N,
                                            float scale) {
  __shared__ float t[32][33];
  int tx = threadIdx.x & 31, ty = threadIdx.x >> 5;
  int n0 = blockIdx.x * 32, k0 = blockIdx.y * 32;
#pragma unroll
  for (int i = 0; i < 32; i += 8)
    t[ty + i][tx] = W[(size_t)(k0 + ty + i) * N + n0 + tx];
  __syncthreads();
#pragma unroll
  for (int i = 0; i < 32; i += 8)
    out[(size_t)(n0 + ty + i) * K + k0 + tx] = f2bf(t[tx][ty + i] * scale);
}

// ---- prep: encoder states f32 (8,109,768) -> bf16 (8,128,768), zero pad rows
__global__ __launch_bounds__(256) void ehs_prep(const float* __restrict__ e,
                                                u16* __restrict__ out) {
  int idx = blockIdx.x * 256 + threadIdx.x;
  if (idx >= BB * SKV_PAD * CDIM / 4) return;
  int c4 = idx * 4;
  int b = c4 / (SKV_PAD * CDIM);
  int rem = c4 - b * (SKV_PAD * CDIM);
  int s = rem / CDIM;
  int c = rem - s * CDIM;
  short4v o = {0, 0, 0, 0};
  if (s < SKV) {
    f32x4 v = *(const f32x4*)(e + ((size_t)b * SKV + s) * CDIM + c);
#pragma unroll
    for (int j = 0; j < 4; j++) o[j] = (short)f2bf(v[j]);
  }
  *(short4v*)&out[c4] = o;
}

// ---- prep: hidden_states f32 -> bf16 (vectorized 8/thread, grid-stride)
__global__ __launch_bounds__(256) void hscvt(const float* __restrict__ in,
                                             u16* __restrict__ out) {
  const size_t total = (size_t)BB * SQ * HDIM;
  size_t step = (size_t)gridDim.x * 256 * 8;
  for (size_t i = ((size_t)blockIdx.x * 256 + threadIdx.x) * 8; i < total;
       i += step) {
    f32x4 a = *(const f32x4*)(in + i);
    f32x4 b = *(const f32x4*)(in + i + 4);
    short8 o;
#pragma unroll
    for (int j = 0; j < 4; j++) {
      o[j] = (short)f2bf(a[j]);
      o[j + 4] = (short)f2bf(b[j]);
    }
    *(short8*)&out[i] = o;
  }
}

// ======================= 256x256 8-phase GEMM (m201 port) ====================
// C = A(MxK) @ Bt(NxK)^T. BK=64, 8 waves (2Mx4N), 512 thr, 128KB LDS dbuf.
// T2: XOR swizzle (row&7)<<3 via pre-swizzled global src + folded read offset.
// T3+T4: 1 half-tile stage per phase; single vmcnt(6) per K-tile.
// Fragment loads are INLINE-ASM ds_read_b128 + manual lgkmcnt(0)/sched_barrier
// fences, so the compiler's waitcnt pass cannot insert conservative vmcnt
// drains against the outstanding LDS-DMA (the r4/r5 stall).
// Region hazard audit: all reads of lds[cur] A complete at P1's fence, B at
// P2's fence; DMA targets those regions only at P2+ (A) / P4 (B). vmcnt(6) at
// P4 retires exactly tile t+1's 4 halves before the phase barrier.

static __device__ __forceinline__ void stage_half(u16* region,
                                                  const u16* gbase, int K,
                                                  int tid) {
#pragma unroll
  for (int j = 0; j < 2; ++j) {
    int c = tid + j * 512;              // 16B chunk index in region
    int s = c ^ ((c >> 3) & 7);         // inverse-swizzled source chunk
    gll16(gbase + (size_t)(s >> 3) * K + (s & 7) * 8, region + c * 8);
  }
}

// MODE 0: bf16 row-major out.  MODE 3: f32 out + bias + residual.
template <int MODE>
__global__ __launch_bounds__(512, 2)
void gemm256(const u16* __restrict__ A, const u16* __restrict__ Bt,
             void* __restrict__ outp, int K, int ntn,
             const float* __restrict__ bias, const float* __restrict__ resid) {
  // [buf][A=0/B=1][half][128*64 elems], region = 16384 B
  __shared__ u16 lds[2][2][2][8192];
  const int tid = threadIdx.x;
  const int wid = tid >> 6, lane = tid & 63;
  const int wm = wid >> 2, wn = wid & 3;
  const int g = lane >> 4, r = lane & 15;

  const int nwg = gridDim.x;
  const int orig = blockIdx.x;
  const int wg = (orig & 7) * (nwg >> 3) + (orig >> 3);  // XCD swizzle
  const int mt = wg / ntn, nt = wg - mt * ntn;
  const int row0 = mt * 256, col0 = nt * 256;

  const u16* Ag = A + (size_t)row0 * K;
  const u16* Bg = Bt + (size_t)col0 * K;
  const int NT = K >> 6;  // K-tiles of 64
  const int brow = (wn & 1) * 64;
  // swizzled, lane-constant column offsets (all read rows are == r mod 8)
  const int swz = (r & 7) << 3;
  const int cx0 = (g * 8) ^ swz;
  const int cx1 = (32 + g * 8) ^ swz;

  // 32-bit LDS byte addresses for the asm ds_reads
  const unsigned lbase = (unsigned)(size_t)(
      __attribute__((address_space(3))) u16*)&lds[0][0][0][0];
  unsigned oa[4][2], ob[2][2];
#pragma unroll
  for (int mi = 0; mi < 4; ++mi) {
    oa[mi][0] = ((mi * 16 + r) * 64 + cx0) * 2;
    oa[mi][1] = ((mi * 16 + r) * 64 + cx1) * 2;
  }
#pragma unroll
  for (int nf = 0; nf < 2; ++nf) {
    ob[nf][0] = ((brow + nf * 16 + r) * 64 + cx0) * 2;
    ob[nf][1] = ((brow + nf * 16 + r) * 64 + cx1) * 2;
  }
  const unsigned regAoff = wm * 16384u;            // + cur*65536
  const unsigned regBoff = 32768u + (wn >> 1) * 16384u;

  f32x4 acc[8][4] = {};

  // ---- prologue: t0 all 4 halves + t1 {A0,A1,B0}; wait for t0 (leave 3)
  stage_half(&lds[0][0][0][0], Ag, K, tid);
  stage_half(&lds[0][0][1][0], Ag + (size_t)128 * K, K, tid);
  stage_half(&lds[0][1][0][0], Bg, K, tid);
  stage_half(&lds[0][1][1][0], Bg + (size_t)128 * K, K, tid);
  stage_half(&lds[1][0][0][0], Ag + 64, K, tid);
  stage_half(&lds[1][0][1][0], Ag + (size_t)128 * K + 64, K, tid);
  stage_half(&lds[1][1][0][0], Bg + 64, K, tid);
  asm volatile("s_waitcnt vmcnt(6)" ::: "memory");
  SBAR();

  for (int t = 0; t < NT; ++t) {
    const int cur = t & 1, nxt = cur ^ 1;
    const unsigned regA = lbase + cur * 65536u + regAoff;
    const unsigned regB = lbase + cur * 65536u + regBoff;
    short8 a0[4][2], a1[4][2], b0[2][2], b1[2][2];

    // ---- P1: asm-read ALL A (16) + b0 (4); stage B1(t+1); MFMA a0 x b0
#pragma unroll
    for (int mi = 0; mi < 4; ++mi) {
      a0[mi][0] = ldsr(regA + oa[mi][0]);
      a0[mi][1] = ldsr(regA + oa[mi][1]);
      a1[mi][0] = ldsr(regA + 8192u + oa[mi][0]);
      a1[mi][1] = ldsr(regA + 8192u + oa[mi][1]);
    }
#pragma unroll
    for (int nf = 0; nf < 2; ++nf) {
      b0[nf][0] = ldsr(regB + ob[nf][0]);
      b0[nf][1] = ldsr(regB + ob[nf][1]);
    }
    if (t + 1 < NT)
      stage_half(&lds[nxt][1][1][0], Bg + (size_t)128 * K + (size_t)(t + 1) * 64,
                 K, tid);
    SBAR();
    asm volatile("s_waitcnt lgkmcnt(0)" ::: "memory");
    __builtin_amdgcn_sched_barrier(0);
    __builtin_amdgcn_s_setprio(1);
#pragma unroll
    for (int mi = 0; mi < 4; ++mi)
#pragma unroll
      for (int nf = 0; nf < 2; ++nf)
#pragma unroll
        for (int ks = 0; ks < 2; ++ks)
          acc[mi][nf] = __builtin_amdgcn_mfma_f32_16x16x32_bf16(
              a0[mi][ks], b0[nf][ks], acc[mi][nf], 0, 0, 0);
    __builtin_amdgcn_sched_barrier(0);
    __builtin_amdgcn_s_setprio(0);
    SBAR();

    // ---- P2: asm-read b1 (4); stage A0(t+2); MFMA a0 x b1
#pragma unroll
    for (int nf = 0; nf < 2; ++nf) {
      b1[nf][0] = ldsr(regB + 4096u + ob[nf][0]);
      b1[nf][1] = ldsr(regB + 4096u + ob[nf][1]);
    }
    if (t + 2 < NT)
      stage_half(&lds[cur][0][0][0], Ag + (size_t)(t + 2) * 64, K, tid);
    SBAR();
    asm volatile("s_waitcnt lgkmcnt(0)" ::: "memory");
    __builtin_amdgcn_sched_barrier(0);
    __builtin_amdgcn_s_setprio(1);
#pragma unroll
    for (int mi = 0; mi < 4; ++mi)
#pragma unroll
      for (int nf = 0; nf < 2; ++nf)
#pragma unroll
        for (int ks = 0; ks < 2; ++ks)
          acc[mi][2 + nf] = __builtin_amdgcn_mfma_f32_16x16x32_bf16(
              a0[mi][ks], b1[nf][ks], acc[mi][2 + nf], 0, 0, 0);
    __builtin_amdgcn_sched_barrier(0);
    __builtin_amdgcn_s_setprio(0);
    SBAR();

    // ---- P3: stage A1(t+2); MFMA a1 x b1  (operands already fenced)
    if (t + 2 < NT)
      stage_half(&lds[cur][0][1][0], Ag + (size_t)128 * K + (size_t)(t + 2) * 64,
                 K, tid);
    SBAR();
    __builtin_amdgcn_s_setprio(1);
#pragma unroll
    for (int mi = 0; mi < 4; ++mi)
#pragma unroll
      for (int nf = 0; nf < 2; ++nf)
#pragma unroll
        for (int ks = 0; ks < 2; ++ks)
          acc[4 + mi][2 + nf] = __builtin_amdgcn_mfma_f32_16x16x32_bf16(
              a1[mi][ks], b1[nf][ks], acc[4 + mi][2 + nf], 0, 0, 0);
    __builtin_amdgcn_sched_barrier(0);
    __builtin_amdgcn_s_setprio(0);
    SBAR();

    // ---- P4: stage B0(t+2); counted vmcnt (3 half-tiles stay in flight)
    if (t + 2 < NT)
      stage_half(&lds[cur][1][0][0], Bg + (size_t)(t + 2) * 64, K, tid);
    if (t < NT - 2)
      asm volatile("s_waitcnt vmcnt(6)" ::: "memory");
    else
      asm volatile("s_waitcnt vmcnt(0)" ::: "memory");
    SBAR();
    __builtin_amdgcn_s_setprio(1);
#pragma unroll
    for (int mi = 0; mi < 4; ++mi)
#pragma unroll
      for (int nf = 0; nf < 2; ++nf)
#pragma unroll
        for (int ks = 0; ks < 2; ++ks)
          acc[4 + mi][nf] = __builtin_amdgcn_mfma_f32_16x16x32_bf16(
              a1[mi][ks], b0[nf][ks], acc[4 + mi][nf], 0, 0, 0);
    __builtin_amdgcn_sched_barrier(0);
    __builtin_amdgcn_s_setprio(0);
    SBAR();
  }

  // ---- epilogue: row = row0+wm*128+am*16+g*4+i, col = col0+wn*64+an*16+r
  if constexpr (MODE == 0) {
    u16* O = (u16*)outp;
#pragma unroll
    for (int am = 0; am < 8; ++am)
#pragma unroll
      for (int i = 0; i < 4; ++i) {
        size_t m = row0 + wm * 128 + am * 16 + g * 4 + i;
        size_t base = m * HDIM + col0 + wn * 64 + r;
#pragma unroll
        for (int an = 0; an < 4; ++an)
          O[base + an * 16] = f2bf(acc[am][an][i]);
      }
  } else {
    float* O = (float*)outp;
#pragma unroll
    for (int am = 0; am < 8; ++am)
#pragma unroll
      for (int i = 0; i < 4; ++i) {
        size_t m = row0 + wm * 128 + am * 16 + g * 4 + i;
        size_t base = m * HDIM + col0 + wn * 64 + r;
#pragma unroll
        for (int an = 0; an < 4; ++an) {
          int col = col0 + wn * 64 + an * 16 + r;
          O[base + an * 16] = acc[am][an][i] + bias[col] + resid[base + an * 16];
        }
      }
  }
}

// ---- m97-structure 128x128 GEMM, kept for the small K/V projections.
// MODE 1: K-heads layout. MODE 2: V^T layout.
template <int MODE>
__global__ __launch_bounds__(256, 4)
void gemm_glds(const u16* __restrict__ A, const u16* __restrict__ Bt,
               void* __restrict__ outp, int K, int ntn) {
  __shared__ u16 Alds[128 * 32];
  __shared__ u16 Blds[128 * 32];
  const int tid = threadIdx.x;
  const int wid = tid >> 6, lane = tid & 63;
  const int wm = wid >> 1, wn = wid & 1;
  const int g = lane >> 4, r = lane & 15;

  const int nwg = gridDim.x;
  const int orig = blockIdx.x;
  const int wg = (orig & 7) * (nwg >> 3) + (orig >> 3);
  const int mt = wg / ntn, nt = wg - mt * ntn;
  const int row0 = mt * 128, col0 = nt * 128;
  const int erow = tid >> 2, ecol = (tid & 3) * 8;

  f32x4 acc[4][4] = {};

  for (int kt = 0; kt < K; kt += 32) {
    const u16* ag = A + (size_t)(row0 + erow) * K + kt + ecol;
    const u16* bg = Bt + (size_t)(col0 + erow) * K + kt + ecol;
    gll16(ag, &Alds[erow * 32 + ecol]);
    gll16(ag + (size_t)64 * K, &Alds[(erow + 64) * 32 + ecol]);
    gll16(bg, &Blds[erow * 32 + ecol]);
    gll16(bg + (size_t)64 * K, &Blds[(erow + 64) * 32 + ecol]);
    __syncthreads();

    short8 afr[4], bfr[4];
#pragma unroll
    for (int mi = 0; mi < 4; mi++)
      afr[mi] = *(short8*)&Alds[(wm * 64 + mi * 16 + r) * 32 + g * 8];
#pragma unroll
    for (int ni = 0; ni < 4; ni++)
      bfr[ni] = *(short8*)&Blds[(wn * 64 + ni * 16 + r) * 32 + g * 8];
#pragma unroll
    for (int mi = 0; mi < 4; mi++)
#pragma unroll
      for (int ni = 0; ni < 4; ni++)
        acc[mi][ni] = __builtin_amdgcn_mfma_f32_16x16x32_bf16(afr[mi], bfr[ni],
                                                              acc[mi][ni], 0, 0, 0);
    __syncthreads();
  }

  u16* O = (u16*)outp;
#pragma unroll
  for (int mi = 0; mi < 4; mi++)
#pragma unroll
    for (int i = 0; i < 4; i++) {
      int m = row0 + wm * 64 + mi * 16 + g * 4 + i;
      int b = m >> 7, skv = m & 127;
#pragma unroll
      for (int ni = 0; ni < 4; ni++) {
        int col = col0 + wn * 64 + ni * 16 + r;
        int hh = col >> 6, d = col & 63;
        size_t addr;
        if constexpr (MODE == 1)
          addr = (((size_t)b * HEADS + hh) * SKV_PAD + skv) * HD + d;
        else
          addr = (((size_t)b * HEADS + hh) * HD + d) * SKV_PAD + skv;
        O[addr] = f2bf(acc[mi][ni][i]);
      }
    }
}

// ---- fused attention: per block = 64 q-rows of one (b,h); 4 waves x 16 rows.
__global__ __launch_bounds__(256, 2)
void attn_kernel(const u16* __restrict__ q, const u16* __restrict__ kh,
                 const u16* __restrict__ vt, u16* __restrict__ o) {
  __shared__ u16 Klds[SKV_T * 72];
  __shared__ u16 Vlds[HD * 136];
  __shared__ u16 Plds[4 * 16 * 136];
  const int tid = threadIdx.x;
  const int wid = tid >> 6, lane = tid & 63;
  const int g = lane >> 4, r = lane & 15;
  const int qt = blockIdx.x;
  const int bh = blockIdx.y;
  const int b = bh / HEADS, h = bh - b * HEADS;

  const u16* kg = kh + (size_t)bh * SKV_PAD * HD;
  for (int i = tid; i < SKV_T * 8; i += 256) {
    int row = i >> 3, c = (i & 7) * 8;
    *(short8*)&Klds[row * 72 + c] = *(const short8*)(kg + row * HD + c);
  }
  const u16* vg = vt + (size_t)bh * HD * SKV_PAD;
  for (int i = tid; i < HD * 16; i += 256) {
    int row = i >> 4, c = (i & 15) * 8;
    *(short8*)&Vlds[row * 136 + c] = *(const short8*)(vg + row * SKV_PAD + c);
  }
  __syncthreads();

  const u16* qg = q + ((size_t)b * SQ + qt * 64 + wid * 16 + r) * HDIM + h * HD + g * 8;
  short8 aq0 = *(const short8*)(qg);
  short8 aq1 = *(const short8*)(qg + 32);

  f32x4 s[7];
#pragma unroll
  for (int nf = 0; nf < 7; nf++) {
    f32x4 z = {0.f, 0.f, 0.f, 0.f};
    short8 k0 = *(short8*)&Klds[(nf * 16 + r) * 72 + g * 8];
    short8 k1 = *(short8*)&Klds[(nf * 16 + r) * 72 + 32 + g * 8];
    z = __builtin_amdgcn_mfma_f32_16x16x32_bf16(aq0, k0, z, 0, 0, 0);
    z = __builtin_amdgcn_mfma_f32_16x16x32_bf16(aq1, k1, z, 0, 0, 0);
    s[nf] = z;
  }

  {
    short4v z = {0, 0, 0, 0};
    *(short4v*)&Plds[(wid * 16 + r) * 136 + 112 + g * 4] = z;
  }

#pragma unroll
  for (int i = 0; i < 4; i++) {
    float pv[7];
    float mx = -1e30f;
#pragma unroll
    for (int nf = 0; nf < 7; nf++) {
      float v = s[nf][i];
      if (nf == 6 && r >= 13) v = -1e30f;
      pv[nf] = v;
      mx = fmaxf(mx, v);
    }
#pragma unroll
    for (int d = 1; d < 16; d <<= 1) mx = fmaxf(mx, __shfl_xor(mx, d, 64));
    float sum = 0.f;
#pragma unroll
    for (int nf = 0; nf < 7; nf++) {
      float e = (nf == 6 && r >= 13) ? 0.f : __expf(pv[nf] - mx);
      pv[nf] = e;
      sum += e;
    }
#pragma unroll
    for (int d = 1; d < 16; d <<= 1) sum += __shfl_xor(sum, d, 64);
    float is = 1.f / sum;
#pragma unroll
    for (int nf = 0; nf < 7; nf++)
      Plds[(wid * 16 + g * 4 + i) * 136 + nf * 16 + r] = f2bf(pv[nf] * is);
  }
  __syncthreads();

  f32x4 oacc[4] = {};
#pragma unroll
  for (int kk = 0; kk < 4; kk++) {
    short8 ap = *(short8*)&Plds[(wid * 16 + r) * 136 + kk * 32 + g * 8];
#pragma unroll
    for (int nf = 0; nf < 4; nf++) {
      short8 bv = *(short8*)&Vlds[(nf * 16 + r) * 136 + kk * 32 + g * 8];
      oacc[nf] = __builtin_amdgcn_mfma_f32_16x16x32_bf16(ap, bv, oacc[nf], 0, 0, 0);
    }
  }
  u16* og = o + ((size_t)b * SQ + qt * 64 + wid * 16) * HDIM + h * HD;
#pragma unroll
  for (int nf = 0; nf < 4; nf++)
#pragma unroll
    for (int i = 0; i < 4; i++)
      og[(size_t)(g * 4 + i) * HDIM + nf * 16 + r] = f2bf(oacc[nf][i]);
}

extern "C" void kernel_launch(void* const* d_in, const int* in_sizes, int n_in,
                              void* d_out, int out_size, void* d_ws, size_t ws_size,
                              hipStream_t stream) {
  const float* hs  = (const float*)d_in[0];
  const float* ehs = (const float*)d_in[1];
  const float* Wq  = (const float*)d_in[2];
  const float* Wk  = (const float*)d_in[3];
  const float* Wv  = (const float*)d_in[4];
  const float* Wo  = (const float*)d_in[5];
  const float* bo  = (const float*)d_in[6];

  char* ws = (char*)d_ws;
  size_t off = 0;
  auto alloc = [&](size_t elems) {
    u16* p = (u16*)(ws + off);
    off += ((elems * 2 + 255) / 256) * 256;
    return p;
  };
  u16* wqt  = alloc((size_t)HDIM * HDIM);
  u16* wot  = alloc((size_t)HDIM * HDIM);
  u16* wkt  = alloc((size_t)HDIM * CDIM);
  u16* wvt  = alloc((size_t)HDIM * CDIM);
  u16* ehsp = alloc((size_t)BB * SKV_PAD * CDIM);
  u16* khb  = alloc((size_t)BB * HEADS * SKV_PAD * HD);
  u16* vtb  = alloc((size_t)BB * HEADS * HD * SKV_PAD);
  u16* qb   = alloc((size_t)BB * SQ * HDIM);
  u16* ao   = alloc((size_t)BB * SQ * HDIM);
  u16* hsb  = ao;  // alias: hsb dead before attention writes ao

  tcvt<<<dim3(HDIM / 32, HDIM / 32), 256, 0, stream>>>(Wq, wqt, HDIM, HDIM, 0.125f);
  tcvt<<<dim3(HDIM / 32, CDIM / 32), 256, 0, stream>>>(Wk, wkt, CDIM, HDIM, 1.0f);
  tcvt<<<dim3(HDIM / 32, CDIM / 32), 256, 0, stream>>>(Wv, wvt, CDIM, HDIM, 1.0f);
  tcvt<<<dim3(HDIM / 32, HDIM / 32), 256, 0, stream>>>(Wo, wot, HDIM, HDIM, 1.0f);
  ehs_prep<<<dim3((BB * SKV_PAD * CDIM / 4 + 255) / 256), 256, 0, stream>>>(ehs, ehsp);
  hscvt<<<dim3(2048), 256, 0, stream>>>(hs, hsb);

  // K,V projections (M = 1024 padded rows; grid 80 % 8 == 0)
  gemm_glds<1><<<dim3(80), 256, 0, stream>>>(ehsp, wkt, khb, CDIM, 10);
  gemm_glds<2><<<dim3(80), 256, 0, stream>>>(ehsp, wvt, vtb, CDIM, 10);
  // Q projection: 256x256 8-phase (grid 128*5 = 640, % 8 == 0)
  gemm256<0><<<dim3(640), 512, 0, stream>>>(hsb, wqt, qb, HDIM, 5, nullptr, nullptr);
  // attention
  attn_kernel<<<dim3(SQ / 64, BB * HEADS), 256, 0, stream>>>(qb, khb, vtb, ao);
  // output projection + bias + f32 residual
  gemm256<3><<<dim3(640), 512, 0, stream>>>(ao, wot, (void*)d_out, HDIM, 5, bo, hs);
}

// Round 7
// 499.719 us; speedup vs baseline: 1.1501x; 1.1501x over previous
//
#include <hip/hip_runtime.h>
#include <hip/hip_bf16.h>

typedef unsigned short u16;
typedef __attribute__((ext_vector_type(8))) short short8;
typedef __attribute__((ext_vector_type(4))) short short4v;
typedef __attribute__((ext_vector_type(4))) float f32x4;

#define HEADS 20
#define HD 64
#define BB 8
#define SQ 4096
#define HDIM 1280
#define SKV 109
#define CDIM 768
#define SKV_PAD 128
#define SKV_T 112

#define SBAR() asm volatile("s_barrier" ::: "memory")

static __device__ __forceinline__ u16 f2bf(float x) {
  union { __hip_bfloat16 h; u16 u; } cv;
  cv.h = __float2bfloat16(x);
  return cv.u;
}

// async global->LDS, 16B per lane (dest = wave-uniform base + lane*16).
static __device__ __forceinline__ void gll16(const void* g, void* l) {
  __builtin_amdgcn_global_load_lds(
      (const __attribute__((address_space(1))) unsigned int*)g,
      (__attribute__((address_space(3))) unsigned int*)l, 16, 0, 0);
}

// inline-asm ds_read_b128 (ordering enforced by explicit lgkmcnt + sched_barrier)
static __device__ __forceinline__ short8 ldsr(unsigned addr) {
  short8 d;
  asm volatile("ds_read_b128 %0, %1" : "=v"(d) : "v"(addr));
  return d;
}

// ---- prep: out[n][k] = bf16(W[k][n] * scale)  (W is K x N row-major)
__global__ __launch_bounds__(256) void tcvt(const float* __restrict__ W,
                                            u16* __restrict__ out, int K, int N,
                                            float scale) {
  __shared__ float t[32][33];
  int tx = threadIdx.x & 31, ty = threadIdx.x >> 5;
  int n0 = blockIdx.x * 32, k0 = blockIdx.y * 32;
#pragma unroll
  for (int i = 0; i < 32; i += 8)
    t[ty + i][tx] = W[(size_t)(k0 + ty + i) * N + n0 + tx];
  __syncthreads();
#pragma unroll
  for (int i = 0; i < 32; i += 8)
    out[(size_t)(n0 + ty + i) * K + k0 + tx] = f2bf(t[tx][ty + i] * scale);
}

// ---- prep: encoder states f32 (8,109,768) -> bf16 (8,128,768), zero pad rows
__global__ __launch_bounds__(256) void ehs_prep(const float* __restrict__ e,
                                                u16* __restrict__ out) {
  int idx = blockIdx.x * 256 + threadIdx.x;
  if (idx >= BB * SKV_PAD * CDIM / 4) return;
  int c4 = idx * 4;
  int b = c4 / (SKV_PAD * CDIM);
  int rem = c4 - b * (SKV_PAD * CDIM);
  int s = rem / CDIM;
  int c = rem - s * CDIM;
  short4v o = {0, 0, 0, 0};
  if (s < SKV) {
    f32x4 v = *(const f32x4*)(e + ((size_t)b * SKV + s) * CDIM + c);
#pragma unroll
    for (int j = 0; j < 4; j++) o[j] = (short)f2bf(v[j]);
  }
  *(short4v*)&out[c4] = o;
}

// ---- prep: hidden_states f32 -> bf16 (vectorized 8/thread, grid-stride)
__global__ __launch_bounds__(256) void hscvt(const float* __restrict__ in,
                                             u16* __restrict__ out) {
  const size_t total = (size_t)BB * SQ * HDIM;
  size_t step = (size_t)gridDim.x * 256 * 8;
  for (size_t i = ((size_t)blockIdx.x * 256 + threadIdx.x) * 8; i < total;
       i += step) {
    f32x4 a = *(const f32x4*)(in + i);
    f32x4 b = *(const f32x4*)(in + i + 4);
    short8 o;
#pragma unroll
    for (int j = 0; j < 4; j++) {
      o[j] = (short)f2bf(a[j]);
      o[j + 4] = (short)f2bf(b[j]);
    }
    *(short8*)&out[i] = o;
  }
}

// ================= 128x128 triple-buffered deep-prefetch GEMM ================
// C = A(MxK) @ Bt(NxK)^T, bf16 MFMA 16x16x32, f32 acc. BK=32, 4 waves (2x2),
// 256 thr. LDS = 3 bufs x 16KB -> 3 blocks/CU (12 waves, 3/SIMD TLP).
// Per tile: [vmcnt(8); SBAR] -> 8 asm ds_read_b128 -> lgkm(0)+sched_barrier ->
// 16 MFMA -> SBAR -> stage tile t+3 into this buf (4 gll16/thread).
// Ledger: outstanding always 12 instrs (3 tiles x 4); vmcnt(8) retires exactly
// tile t. Prefetch distance ~2 full tiles > HBM latency. Stage-after-barrier
// makes DMA-write vs ds_read hazard safe (all waves passed lgkmcnt(0)).
// Swizzle: col-chunk ^= (row>>1)&3 on DMA *source* and read col (involution).
// MODE 0: bf16 row-major out. MODE 3: f32 out + bias + residual.

static __device__ __forceinline__ void stage128(u16* __restrict__ Ar,
                                                u16* __restrict__ Br,
                                                const u16* __restrict__ Ag,
                                                const u16* __restrict__ Bg,
                                                int K, int kt, int tid) {
#pragma unroll
  for (int j = 0; j < 2; ++j) {
    int c = tid + j * 256;        // 16B chunk in 8KB region
    int row = c >> 2, gc = c & 3;
    int sc = gc ^ ((row >> 1) & 3);
    gll16(Ag + (size_t)row * K + kt + sc * 8, Ar + c * 8);
    gll16(Bg + (size_t)row * K + kt + sc * 8, Br + c * 8);
  }
}

template <int MODE>
__global__ __launch_bounds__(256, 4)
void gemm_tb(const u16* __restrict__ A, const u16* __restrict__ Bt,
             void* __restrict__ outp, int K, int ntn,
             const float* __restrict__ bias, const float* __restrict__ resid) {
  __shared__ u16 lds[3][8192];  // per buf: A elems [0,4096), B elems [4096,8192)
  const int tid = threadIdx.x;
  const int wid = tid >> 6, lane = tid & 63;
  const int wm = wid >> 1, wn = wid & 1;
  const int g = lane >> 4, r = lane & 15;

  const int nwg = gridDim.x;
  const int orig = blockIdx.x;
  const int wg = (orig & 7) * (nwg >> 3) + (orig >> 3);  // XCD swizzle
  const int mt = wg / ntn, nt = wg - mt * ntn;
  const int row0 = mt * 128, col0 = nt * 128;

  const u16* Ag = A + (size_t)row0 * K;
  const u16* Bg = Bt + (size_t)col0 * K;
  const int NT = K >> 5;

  // swizzled lane-constant read column (row & 7 == r & 7 for all frag rows)
  const int cx = (g * 8) ^ (((r >> 1) & 3) << 3);
  const unsigned lbase = (unsigned)(size_t)(
      __attribute__((address_space(3))) u16*)&lds[0][0];
  unsigned aoff[4], boff[4];
#pragma unroll
  for (int mi = 0; mi < 4; ++mi)
    aoff[mi] = ((wm * 64 + mi * 16 + r) * 32 + cx) * 2;
#pragma unroll
  for (int ni = 0; ni < 4; ++ni)
    boff[ni] = (4096 + (wn * 64 + ni * 16 + r) * 32 + cx) * 2;

  f32x4 acc[4][4] = {};

  // prologue: stage tiles 0,1,2 into bufs 0,1,2 (12 instrs/thread outstanding)
  stage128(&lds[0][0], &lds[0][4096], Ag, Bg, K, 0, tid);
  stage128(&lds[1][0], &lds[1][4096], Ag, Bg, K, 32, tid);
  stage128(&lds[2][0], &lds[2][4096], Ag, Bg, K, 64, tid);

  int buf = 0;
  for (int t = 0; t < NT; ++t) {
    // tile t guaranteed landed once each wave's oldest 4 DMA instrs retire
    asm volatile("s_waitcnt vmcnt(8)" ::: "memory");
    SBAR();
    const unsigned base = lbase + buf * 16384u;
    short8 a[4], b[4];
#pragma unroll
    for (int mi = 0; mi < 4; ++mi) a[mi] = ldsr(base + aoff[mi]);
#pragma unroll
    for (int ni = 0; ni < 4; ++ni) b[ni] = ldsr(base + boff[ni]);
    asm volatile("s_waitcnt lgkmcnt(0)" ::: "memory");
    __builtin_amdgcn_sched_barrier(0);
    __builtin_amdgcn_s_setprio(1);
#pragma unroll
    for (int mi = 0; mi < 4; ++mi)
#pragma unroll
      for (int ni = 0; ni < 4; ++ni)
        acc[mi][ni] = __builtin_amdgcn_mfma_f32_16x16x32_bf16(a[mi], b[ni],
                                                              acc[mi][ni], 0, 0, 0);
    __builtin_amdgcn_s_setprio(0);
    SBAR();  // all waves' reads of buf complete -> safe to DMA-overwrite
    const int kt3 = (t + 3 < NT) ? (t + 3) * 32 : 0;  // clamp: constant ledger
    stage128(&lds[buf][0], &lds[buf][4096], Ag, Bg, K, kt3, tid);
    buf = (buf == 2) ? 0 : buf + 1;
  }

  // epilogue: D row = row0 + wm*64 + mi*16 + g*4 + i, col = col0 + wn*64 + ni*16 + r
  if constexpr (MODE == 0) {
    u16* O = (u16*)outp;
#pragma unroll
    for (int mi = 0; mi < 4; ++mi)
#pragma unroll
      for (int i = 0; i < 4; ++i) {
        size_t m = row0 + wm * 64 + mi * 16 + g * 4 + i;
        size_t base = m * HDIM + col0 + wn * 64 + r;
#pragma unroll
        for (int ni = 0; ni < 4; ++ni)
          O[base + ni * 16] = f2bf(acc[mi][ni][i]);
      }
  } else {
    float* O = (float*)outp;
#pragma unroll
    for (int mi = 0; mi < 4; ++mi)
#pragma unroll
      for (int i = 0; i < 4; ++i) {
        size_t m = row0 + wm * 64 + mi * 16 + g * 4 + i;
        size_t base = m * HDIM + col0 + wn * 64 + r;
#pragma unroll
        for (int ni = 0; ni < 4; ++ni) {
          int col = col0 + wn * 64 + ni * 16 + r;
          O[base + ni * 16] = acc[mi][ni][i] + bias[col] + resid[base + ni * 16];
        }
      }
  }
}

// ---- m97-structure 128x128 GEMM, kept for the small K/V projections.
// MODE 1: K-heads layout. MODE 2: V^T layout.
template <int MODE>
__global__ __launch_bounds__(256, 4)
void gemm_glds(const u16* __restrict__ A, const u16* __restrict__ Bt,
               void* __restrict__ outp, int K, int ntn) {
  __shared__ u16 Alds[128 * 32];
  __shared__ u16 Blds[128 * 32];
  const int tid = threadIdx.x;
  const int wid = tid >> 6, lane = tid & 63;
  const int wm = wid >> 1, wn = wid & 1;
  const int g = lane >> 4, r = lane & 15;

  const int nwg = gridDim.x;
  const int orig = blockIdx.x;
  const int wg = (orig & 7) * (nwg >> 3) + (orig >> 3);
  const int mt = wg / ntn, nt = wg - mt * ntn;
  const int row0 = mt * 128, col0 = nt * 128;
  const int erow = tid >> 2, ecol = (tid & 3) * 8;

  f32x4 acc[4][4] = {};

  for (int kt = 0; kt < K; kt += 32) {
    const u16* ag = A + (size_t)(row0 + erow) * K + kt + ecol;
    const u16* bg = Bt + (size_t)(col0 + erow) * K + kt + ecol;
    gll16(ag, &Alds[erow * 32 + ecol]);
    gll16(ag + (size_t)64 * K, &Alds[(erow + 64) * 32 + ecol]);
    gll16(bg, &Blds[erow * 32 + ecol]);
    gll16(bg + (size_t)64 * K, &Blds[(erow + 64) * 32 + ecol]);
    __syncthreads();

    short8 afr[4], bfr[4];
#pragma unroll
    for (int mi = 0; mi < 4; mi++)
      afr[mi] = *(short8*)&Alds[(wm * 64 + mi * 16 + r) * 32 + g * 8];
#pragma unroll
    for (int ni = 0; ni < 4; ni++)
      bfr[ni] = *(short8*)&Blds[(wn * 64 + ni * 16 + r) * 32 + g * 8];
#pragma unroll
    for (int mi = 0; mi < 4; mi++)
#pragma unroll
      for (int ni = 0; ni < 4; ni++)
        acc[mi][ni] = __builtin_amdgcn_mfma_f32_16x16x32_bf16(afr[mi], bfr[ni],
                                                              acc[mi][ni], 0, 0, 0);
    __syncthreads();
  }

  u16* O = (u16*)outp;
#pragma unroll
  for (int mi = 0; mi < 4; mi++)
#pragma unroll
    for (int i = 0; i < 4; i++) {
      int m = row0 + wm * 64 + mi * 16 + g * 4 + i;
      int b = m >> 7, skv = m & 127;
#pragma unroll
      for (int ni = 0; ni < 4; ni++) {
        int col = col0 + wn * 64 + ni * 16 + r;
        int hh = col >> 6, d = col & 63;
        size_t addr;
        if constexpr (MODE == 1)
          addr = (((size_t)b * HEADS + hh) * SKV_PAD + skv) * HD + d;
        else
          addr = (((size_t)b * HEADS + hh) * HD + d) * SKV_PAD + skv;
        O[addr] = f2bf(acc[mi][ni][i]);
      }
    }
}

// ---- fused attention: per block = 64 q-rows of one (b,h); 4 waves x 16 rows.
__global__ __launch_bounds__(256, 2)
void attn_kernel(const u16* __restrict__ q, const u16* __restrict__ kh,
                 const u16* __restrict__ vt, u16* __restrict__ o) {
  __shared__ u16 Klds[SKV_T * 72];
  __shared__ u16 Vlds[HD * 136];
  __shared__ u16 Plds[4 * 16 * 136];
  const int tid = threadIdx.x;
  const int wid = tid >> 6, lane = tid & 63;
  const int g = lane >> 4, r = lane & 15;
  const int qt = blockIdx.x;
  const int bh = blockIdx.y;
  const int b = bh / HEADS, h = bh - b * HEADS;

  const u16* kg = kh + (size_t)bh * SKV_PAD * HD;
  for (int i = tid; i < SKV_T * 8; i += 256) {
    int row = i >> 3, c = (i & 7) * 8;
    *(short8*)&Klds[row * 72 + c] = *(const short8*)(kg + row * HD + c);
  }
  const u16* vg = vt + (size_t)bh * HD * SKV_PAD;
  for (int i = tid; i < HD * 16; i += 256) {
    int row = i >> 4, c = (i & 15) * 8;
    *(short8*)&Vlds[row * 136 + c] = *(const short8*)(vg + row * SKV_PAD + c);
  }
  __syncthreads();

  const u16* qg = q + ((size_t)b * SQ + qt * 64 + wid * 16 + r) * HDIM + h * HD + g * 8;
  short8 aq0 = *(const short8*)(qg);
  short8 aq1 = *(const short8*)(qg + 32);

  f32x4 s[7];
#pragma unroll
  for (int nf = 0; nf < 7; nf++) {
    f32x4 z = {0.f, 0.f, 0.f, 0.f};
    short8 k0 = *(short8*)&Klds[(nf * 16 + r) * 72 + g * 8];
    short8 k1 = *(short8*)&Klds[(nf * 16 + r) * 72 + 32 + g * 8];
    z = __builtin_amdgcn_mfma_f32_16x16x32_bf16(aq0, k0, z, 0, 0, 0);
    z = __builtin_amdgcn_mfma_f32_16x16x32_bf16(aq1, k1, z, 0, 0, 0);
    s[nf] = z;
  }

  {
    short4v z = {0, 0, 0, 0};
    *(short4v*)&Plds[(wid * 16 + r) * 136 + 112 + g * 4] = z;
  }

#pragma unroll
  for (int i = 0; i < 4; i++) {
    float pv[7];
    float mx = -1e30f;
#pragma unroll
    for (int nf = 0; nf < 7; nf++) {
      float v = s[nf][i];
      if (nf == 6 && r >= 13) v = -1e30f;
      pv[nf] = v;
      mx = fmaxf(mx, v);
    }
#pragma unroll
    for (int d = 1; d < 16; d <<= 1) mx = fmaxf(mx, __shfl_xor(mx, d, 64));
    float sum = 0.f;
#pragma unroll
    for (int nf = 0; nf < 7; nf++) {
      float e = (nf == 6 && r >= 13) ? 0.f : __expf(pv[nf] - mx);
      pv[nf] = e;
      sum += e;
    }
#pragma unroll
    for (int d = 1; d < 16; d <<= 1) sum += __shfl_xor(sum, d, 64);
    float is = 1.f / sum;
#pragma unroll
    for (int nf = 0; nf < 7; nf++)
      Plds[(wid * 16 + g * 4 + i) * 136 + nf * 16 + r] = f2bf(pv[nf] * is);
  }
  __syncthreads();

  f32x4 oacc[4] = {};
#pragma unroll
  for (int kk = 0; kk < 4; kk++) {
    short8 ap = *(short8*)&Plds[(wid * 16 + r) * 136 + kk * 32 + g * 8];
#pragma unroll
    for (int nf = 0; nf < 4; nf++) {
      short8 bv = *(short8*)&Vlds[(nf * 16 + r) * 136 + kk * 32 + g * 8];
      oacc[nf] = __builtin_amdgcn_mfma_f32_16x16x32_bf16(ap, bv, oacc[nf], 0, 0, 0);
    }
  }
  u16* og = o + ((size_t)b * SQ + qt * 64 + wid * 16) * HDIM + h * HD;
#pragma unroll
  for (int nf = 0; nf < 4; nf++)
#pragma unroll
    for (int i = 0; i < 4; i++)
      og[(size_t)(g * 4 + i) * HDIM + nf * 16 + r] = f2bf(oacc[nf][i]);
}

extern "C" void kernel_launch(void* const* d_in, const int* in_sizes, int n_in,
                              void* d_out, int out_size, void* d_ws, size_t ws_size,
                              hipStream_t stream) {
  const float* hs  = (const float*)d_in[0];
  const float* ehs = (const float*)d_in[1];
  const float* Wq  = (const float*)d_in[2];
  const float* Wk  = (const float*)d_in[3];
  const float* Wv  = (const float*)d_in[4];
  const float* Wo  = (const float*)d_in[5];
  const float* bo  = (const float*)d_in[6];

  char* ws = (char*)d_ws;
  size_t off = 0;
  auto alloc = [&](size_t elems) {
    u16* p = (u16*)(ws + off);
    off += ((elems * 2 + 255) / 256) * 256;
    return p;
  };
  u16* wqt  = alloc((size_t)HDIM * HDIM);
  u16* wot  = alloc((size_t)HDIM * HDIM);
  u16* wkt  = alloc((size_t)HDIM * CDIM);
  u16* wvt  = alloc((size_t)HDIM * CDIM);
  u16* ehsp = alloc((size_t)BB * SKV_PAD * CDIM);
  u16* khb  = alloc((size_t)BB * HEADS * SKV_PAD * HD);
  u16* vtb  = alloc((size_t)BB * HEADS * HD * SKV_PAD);
  u16* qb   = alloc((size_t)BB * SQ * HDIM);
  u16* ao   = alloc((size_t)BB * SQ * HDIM);
  u16* hsb  = ao;  // alias: hsb dead before attention writes ao

  tcvt<<<dim3(HDIM / 32, HDIM / 32), 256, 0, stream>>>(Wq, wqt, HDIM, HDIM, 0.125f);
  tcvt<<<dim3(HDIM / 32, CDIM / 32), 256, 0, stream>>>(Wk, wkt, CDIM, HDIM, 1.0f);
  tcvt<<<dim3(HDIM / 32, CDIM / 32), 256, 0, stream>>>(Wv, wvt, CDIM, HDIM, 1.0f);
  tcvt<<<dim3(HDIM / 32, HDIM / 32), 256, 0, stream>>>(Wo, wot, HDIM, HDIM, 1.0f);
  ehs_prep<<<dim3((BB * SKV_PAD * CDIM / 4 + 255) / 256), 256, 0, stream>>>(ehs, ehsp);
  hscvt<<<dim3(2048), 256, 0, stream>>>(hs, hsb);

  // K,V projections (M = 1024 padded rows; grid 80 % 8 == 0)
  gemm_glds<1><<<dim3(80), 256, 0, stream>>>(ehsp, wkt, khb, CDIM, 10);
  gemm_glds<2><<<dim3(80), 256, 0, stream>>>(ehsp, wvt, vtb, CDIM, 10);
  // Q projection: 128x128 triple-buffer deep-prefetch (grid 2560 % 8 == 0)
  gemm_tb<0><<<dim3(2560), 256, 0, stream>>>(hsb, wqt, qb, HDIM, 10, nullptr, nullptr);
  // attention
  attn_kernel<<<dim3(SQ / 64, BB * HEADS), 256, 0, stream>>>(qb, khb, vtb, ao);
  // output projection + bias + f32 residual
  gemm_tb<3><<<dim3(2560), 256, 0, stream>>>(ao, wot, (void*)d_out, HDIM, 10, bo, hs);
}

// Round 8
// 442.349 us; speedup vs baseline: 1.2992x; 1.1297x over previous
//
#include <hip/hip_runtime.h>
#include <hip/hip_bf16.h>

typedef unsigned short u16;
typedef __attribute__((ext_vector_type(8))) short short8;
typedef __attribute__((ext_vector_type(4))) short short4v;
typedef __attribute__((ext_vector_type(4))) float f32x4;

#define HEADS 20
#define HD 64
#define BB 8
#define SQ 4096
#define HDIM 1280
#define SKV 109
#define CDIM 768
#define SKV_PAD 128
#define SKV_T 112

#define SBAR() asm volatile("s_barrier" ::: "memory")

static __device__ __forceinline__ u16 f2bf(float x) {
  union { __hip_bfloat16 h; u16 u; } cv;
  cv.h = __float2bfloat16(x);
  return cv.u;
}

// async global->LDS, 16B per lane (dest = wave-uniform base + lane*16).
static __device__ __forceinline__ void gll16(const void* g, void* l) {
  __builtin_amdgcn_global_load_lds(
      (const __attribute__((address_space(1))) unsigned int*)g,
      (__attribute__((address_space(3))) unsigned int*)l, 16, 0, 0);
}

// ---- prep: out[n][k] = bf16(W[k][n] * scale)  (W is K x N row-major)
__global__ __launch_bounds__(256) void tcvt(const float* __restrict__ W,
                                            u16* __restrict__ out, int K, int N,
                                            float scale) {
  __shared__ float t[32][33];
  int tx = threadIdx.x & 31, ty = threadIdx.x >> 5;
  int n0 = blockIdx.x * 32, k0 = blockIdx.y * 32;
#pragma unroll
  for (int i = 0; i < 32; i += 8)
    t[ty + i][tx] = W[(size_t)(k0 + ty + i) * N + n0 + tx];
  __syncthreads();
#pragma unroll
  for (int i = 0; i < 32; i += 8)
    out[(size_t)(n0 + ty + i) * K + k0 + tx] = f2bf(t[tx][ty + i] * scale);
}

// ---- prep: encoder states f32 (8,109,768) -> bf16 (8,128,768), zero pad rows
__global__ __launch_bounds__(256) void ehs_prep(const float* __restrict__ e,
                                                u16* __restrict__ out) {
  int idx = blockIdx.x * 256 + threadIdx.x;
  if (idx >= BB * SKV_PAD * CDIM / 4) return;
  int c4 = idx * 4;
  int b = c4 / (SKV_PAD * CDIM);
  int rem = c4 - b * (SKV_PAD * CDIM);
  int s = rem / CDIM;
  int c = rem - s * CDIM;
  short4v o = {0, 0, 0, 0};
  if (s < SKV) {
    f32x4 v = *(const f32x4*)(e + ((size_t)b * SKV + s) * CDIM + c);
#pragma unroll
    for (int j = 0; j < 4; j++) o[j] = (short)f2bf(v[j]);
  }
  *(short4v*)&out[c4] = o;
}

// ---- prep: hidden_states f32 -> bf16 (vectorized 8/thread, grid-stride)
__global__ __launch_bounds__(256) void hscvt(const float* __restrict__ in,
                                             u16* __restrict__ out) {
  const size_t total = (size_t)BB * SQ * HDIM;
  size_t step = (size_t)gridDim.x * 256 * 8;
  for (size_t i = ((size_t)blockIdx.x * 256 + threadIdx.x) * 8; i < total;
       i += step) {
    f32x4 a = *(const f32x4*)(in + i);
    f32x4 b = *(const f32x4*)(in + i + 4);
    short8 o;
#pragma unroll
    for (int j = 0; j < 4; j++) {
      o[j] = (short)f2bf(a[j]);
      o[j + 4] = (short)f2bf(b[j]);
    }
    *(short8*)&out[i] = o;
  }
}

// ============ 128x256 tile, BK=32, 3-buffer counted-vmcnt GEMM ===============
// C = A(MxK) @ Bt(NxK)^T, bf16 MFMA 16x16x32, f32 acc.
// 8 waves (2M x 4N), wave owns 64x64 -> acc = 4x4 f32x4 = 64 regs.
// __launch_bounds__(512,4): reg cap 128 -> 2 blocks/CU (16 waves) for
// cross-block TLP (r3's proven lever) ON TOP of counted-vmcnt pipelining
// (r4's proven lever). LDS = 3 bufs x (128+256)x32 x 2B = 72 KB.
// Per tile: stage t+2 (3 gll16) -> 8 plain ds_reads -> 16 MFMA ->
// vmcnt(3) [retires tile t+1 exactly; ledger: 6 outstanding, oldest 3 = t+1]
// -> s_barrier. ONE barrier/tile; no mid-tile hazard (reads are read-only,
// stage target buf[(t+2)%3] was last read at t-1, fenced by t-1's barrier).
// Swizzle (r7-verified, conflicts=0): chunk ^= (row>>1)&3 on DMA source and
// read column -> 2-way bank aliasing only (free, m136).
// MODE 0: bf16 row-major out. MODE 3: f32 out + bias + residual.

template <int MODE>
__global__ __launch_bounds__(512, 4)
void gemm_v2(const u16* __restrict__ A, const u16* __restrict__ Bt,
             void* __restrict__ outp, int K, int ntn,
             const float* __restrict__ bias, const float* __restrict__ resid) {
  // per buf: A elems [0,4096) = 128x32, B elems [4096,12288) = 256x32
  __shared__ u16 lds[3][12288];
  const int tid = threadIdx.x;
  const int wid = tid >> 6, lane = tid & 63;
  const int wm = wid >> 2, wn = wid & 3;
  const int g = lane >> 4, r = lane & 15;

  const int nwg = gridDim.x;
  const int orig = blockIdx.x;
  const int wg = (orig & 7) * (nwg >> 3) + (orig >> 3);  // XCD swizzle
  const int mt = wg / ntn, nt = wg - mt * ntn;
  const int row0 = mt * 128, col0 = nt * 256;

  const u16* Ag = A + (size_t)row0 * K;
  const u16* Bg = Bt + (size_t)col0 * K;
  const int NT = K >> 5;

  // swizzled lane-constant read column (all frag rows == r mod 16)
  const int cx = (g * 8) ^ (((r >> 1) & 3) << 3);

  // staging: A = 512 chunks (1/thread), B = 1024 chunks (2/thread)
  const int sa_row = tid >> 2;
  const int sa_sc = (tid & 3) ^ ((tid >> 3) & 3);
  const int sb_row1 = (tid + 512) >> 2;
  const int sb_sc1 = ((tid + 512) & 3) ^ (((tid + 512) >> 3) & 3);

  f32x4 acc[4][4] = {};

  auto stage = [&](int buf, int kt) {
    gll16(Ag + (size_t)sa_row * K + kt + sa_sc * 8, &lds[buf][tid * 8]);
    gll16(Bg + (size_t)sa_row * K + kt + sa_sc * 8, &lds[buf][4096 + tid * 8]);
    gll16(Bg + (size_t)sb_row1 * K + kt + sb_sc1 * 8,
          &lds[buf][4096 + (tid + 512) * 8]);
  };

  // prologue: stage tiles 0,1 (6 instrs); vmcnt(3) retires tile 0
  stage(0, 0);
  stage(1, 32);
  asm volatile("s_waitcnt vmcnt(3)" ::: "memory");
  SBAR();

  int buf = 0;
  for (int t = 0; t < NT; ++t) {
    int nb = buf + 2;
    if (nb >= 3) nb -= 3;
    if (t + 2 < NT) stage(nb, (t + 2) * 32);

    short8 a[4], b[4];
#pragma unroll
    for (int mi = 0; mi < 4; ++mi)
      a[mi] = *(short8*)&lds[buf][(wm * 64 + mi * 16 + r) * 32 + cx];
#pragma unroll
    for (int nf = 0; nf < 4; ++nf)
      b[nf] = *(short8*)&lds[buf][4096 + (wn * 64 + nf * 16 + r) * 32 + cx];

    __builtin_amdgcn_s_setprio(1);
#pragma unroll
    for (int mi = 0; mi < 4; ++mi)
#pragma unroll
      for (int nf = 0; nf < 4; ++nf)
        acc[mi][nf] = __builtin_amdgcn_mfma_f32_16x16x32_bf16(a[mi], b[nf],
                                                              acc[mi][nf], 0, 0, 0);
    __builtin_amdgcn_s_setprio(0);

    if (t < NT - 2)
      asm volatile("s_waitcnt vmcnt(3)" ::: "memory");
    else
      asm volatile("s_waitcnt vmcnt(0)" ::: "memory");
    SBAR();
    buf = (buf + 1 == 3) ? 0 : buf + 1;
  }

  // epilogue: row = row0 + wm*64 + mi*16 + g*4 + i, col = col0 + wn*64 + nf*16 + r
  if constexpr (MODE == 0) {
    u16* O = (u16*)outp;
#pragma unroll
    for (int mi = 0; mi < 4; ++mi)
#pragma unroll
      for (int i = 0; i < 4; ++i) {
        size_t m = row0 + wm * 64 + mi * 16 + g * 4 + i;
        size_t base = m * HDIM + col0 + wn * 64 + r;
#pragma unroll
        for (int nf = 0; nf < 4; ++nf)
          O[base + nf * 16] = f2bf(acc[mi][nf][i]);
      }
  } else {
    float* O = (float*)outp;
#pragma unroll
    for (int mi = 0; mi < 4; ++mi)
#pragma unroll
      for (int i = 0; i < 4; ++i) {
        size_t m = row0 + wm * 64 + mi * 16 + g * 4 + i;
        size_t base = m * HDIM + col0 + wn * 64 + r;
#pragma unroll
        for (int nf = 0; nf < 4; ++nf) {
          int col = col0 + wn * 64 + nf * 16 + r;
          O[base + nf * 16] = acc[mi][nf][i] + bias[col] + resid[base + nf * 16];
        }
      }
  }
}

// ---- m97-structure 128x128 GEMM, kept for the small K/V projections.
// MODE 1: K-heads layout. MODE 2: V^T layout.
template <int MODE>
__global__ __launch_bounds__(256, 4)
void gemm_glds(const u16* __restrict__ A, const u16* __restrict__ Bt,
               void* __restrict__ outp, int K, int ntn) {
  __shared__ u16 Alds[128 * 32];
  __shared__ u16 Blds[128 * 32];
  const int tid = threadIdx.x;
  const int wid = tid >> 6, lane = tid & 63;
  const int wm = wid >> 1, wn = wid & 1;
  const int g = lane >> 4, r = lane & 15;

  const int nwg = gridDim.x;
  const int orig = blockIdx.x;
  const int wg = (orig & 7) * (nwg >> 3) + (orig >> 3);
  const int mt = wg / ntn, nt = wg - mt * ntn;
  const int row0 = mt * 128, col0 = nt * 128;
  const int erow = tid >> 2, ecol = (tid & 3) * 8;

  f32x4 acc[4][4] = {};

  for (int kt = 0; kt < K; kt += 32) {
    const u16* ag = A + (size_t)(row0 + erow) * K + kt + ecol;
    const u16* bg = Bt + (size_t)(col0 + erow) * K + kt + ecol;
    gll16(ag, &Alds[erow * 32 + ecol]);
    gll16(ag + (size_t)64 * K, &Alds[(erow + 64) * 32 + ecol]);
    gll16(bg, &Blds[erow * 32 + ecol]);
    gll16(bg + (size_t)64 * K, &Blds[(erow + 64) * 32 + ecol]);
    __syncthreads();

    short8 afr[4], bfr[4];
#pragma unroll
    for (int mi = 0; mi < 4; mi++)
      afr[mi] = *(short8*)&Alds[(wm * 64 + mi * 16 + r) * 32 + g * 8];
#pragma unroll
    for (int ni = 0; ni < 4; ni++)
      bfr[ni] = *(short8*)&Blds[(wn * 64 + ni * 16 + r) * 32 + g * 8];
#pragma unroll
    for (int mi = 0; mi < 4; mi++)
#pragma unroll
      for (int ni = 0; ni < 4; ni++)
        acc[mi][ni] = __builtin_amdgcn_mfma_f32_16x16x32_bf16(afr[mi], bfr[ni],
                                                              acc[mi][ni], 0, 0, 0);
    __syncthreads();
  }

  u16* O = (u16*)outp;
#pragma unroll
  for (int mi = 0; mi < 4; mi++)
#pragma unroll
    for (int i = 0; i < 4; i++) {
      int m = row0 + wm * 64 + mi * 16 + g * 4 + i;
      int b = m >> 7, skv = m & 127;
#pragma unroll
      for (int ni = 0; ni < 4; ni++) {
        int col = col0 + wn * 64 + ni * 16 + r;
        int hh = col >> 6, d = col & 63;
        size_t addr;
        if constexpr (MODE == 1)
          addr = (((size_t)b * HEADS + hh) * SKV_PAD + skv) * HD + d;
        else
          addr = (((size_t)b * HEADS + hh) * HD + d) * SKV_PAD + skv;
        O[addr] = f2bf(acc[mi][ni][i]);
      }
    }
}

// ---- fused attention: per block = 64 q-rows of one (b,h); 4 waves x 16 rows.
__global__ __launch_bounds__(256, 2)
void attn_kernel(const u16* __restrict__ q, const u16* __restrict__ kh,
                 const u16* __restrict__ vt, u16* __restrict__ o) {
  __shared__ u16 Klds[SKV_T * 72];
  __shared__ u16 Vlds[HD * 136];
  __shared__ u16 Plds[4 * 16 * 136];
  const int tid = threadIdx.x;
  const int wid = tid >> 6, lane = tid & 63;
  const int g = lane >> 4, r = lane & 15;
  const int qt = blockIdx.x;
  const int bh = blockIdx.y;
  const int b = bh / HEADS, h = bh - b * HEADS;

  const u16* kg = kh + (size_t)bh * SKV_PAD * HD;
  for (int i = tid; i < SKV_T * 8; i += 256) {
    int row = i >> 3, c = (i & 7) * 8;
    *(short8*)&Klds[row * 72 + c] = *(const short8*)(kg + row * HD + c);
  }
  const u16* vg = vt + (size_t)bh * HD * SKV_PAD;
  for (int i = tid; i < HD * 16; i += 256) {
    int row = i >> 4, c = (i & 15) * 8;
    *(short8*)&Vlds[row * 136 + c] = *(const short8*)(vg + row * SKV_PAD + c);
  }
  __syncthreads();

  const u16* qg = q + ((size_t)b * SQ + qt * 64 + wid * 16 + r) * HDIM + h * HD + g * 8;
  short8 aq0 = *(const short8*)(qg);
  short8 aq1 = *(const short8*)(qg + 32);

  f32x4 s[7];
#pragma unroll
  for (int nf = 0; nf < 7; nf++) {
    f32x4 z = {0.f, 0.f, 0.f, 0.f};
    short8 k0 = *(short8*)&Klds[(nf * 16 + r) * 72 + g * 8];
    short8 k1 = *(short8*)&Klds[(nf * 16 + r) * 72 + 32 + g * 8];
    z = __builtin_amdgcn_mfma_f32_16x16x32_bf16(aq0, k0, z, 0, 0, 0);
    z = __builtin_amdgcn_mfma_f32_16x16x32_bf16(aq1, k1, z, 0, 0, 0);
    s[nf] = z;
  }

  {
    short4v z = {0, 0, 0, 0};
    *(short4v*)&Plds[(wid * 16 + r) * 136 + 112 + g * 4] = z;
  }

#pragma unroll
  for (int i = 0; i < 4; i++) {
    float pv[7];
    float mx = -1e30f;
#pragma unroll
    for (int nf = 0; nf < 7; nf++) {
      float v = s[nf][i];
      if (nf == 6 && r >= 13) v = -1e30f;
      pv[nf] = v;
      mx = fmaxf(mx, v);
    }
#pragma unroll
    for (int d = 1; d < 16; d <<= 1) mx = fmaxf(mx, __shfl_xor(mx, d, 64));
    float sum = 0.f;
#pragma unroll
    for (int nf = 0; nf < 7; nf++) {
      float e = (nf == 6 && r >= 13) ? 0.f : __expf(pv[nf] - mx);
      pv[nf] = e;
      sum += e;
    }
#pragma unroll
    for (int d = 1; d < 16; d <<= 1) sum += __shfl_xor(sum, d, 64);
    float is = 1.f / sum;
#pragma unroll
    for (int nf = 0; nf < 7; nf++)
      Plds[(wid * 16 + g * 4 + i) * 136 + nf * 16 + r] = f2bf(pv[nf] * is);
  }
  __syncthreads();

  f32x4 oacc[4] = {};
#pragma unroll
  for (int kk = 0; kk < 4; kk++) {
    short8 ap = *(short8*)&Plds[(wid * 16 + r) * 136 + kk * 32 + g * 8];
#pragma unroll
    for (int nf = 0; nf < 4; nf++) {
      short8 bv = *(short8*)&Vlds[(nf * 16 + r) * 136 + kk * 32 + g * 8];
      oacc[nf] = __builtin_amdgcn_mfma_f32_16x16x32_bf16(ap, bv, oacc[nf], 0, 0, 0);
    }
  }
  u16* og = o + ((size_t)b * SQ + qt * 64 + wid * 16) * HDIM + h * HD;
#pragma unroll
  for (int nf = 0; nf < 4; nf++)
#pragma unroll
    for (int i = 0; i < 4; i++)
      og[(size_t)(g * 4 + i) * HDIM + nf * 16 + r] = f2bf(oacc[nf][i]);
}

extern "C" void kernel_launch(void* const* d_in, const int* in_sizes, int n_in,
                              void* d_out, int out_size, void* d_ws, size_t ws_size,
                              hipStream_t stream) {
  const float* hs  = (const float*)d_in[0];
  const float* ehs = (const float*)d_in[1];
  const float* Wq  = (const float*)d_in[2];
  const float* Wk  = (const float*)d_in[3];
  const float* Wv  = (const float*)d_in[4];
  const float* Wo  = (const float*)d_in[5];
  const float* bo  = (const float*)d_in[6];

  char* ws = (char*)d_ws;
  size_t off = 0;
  auto alloc = [&](size_t elems) {
    u16* p = (u16*)(ws + off);
    off += ((elems * 2 + 255) / 256) * 256;
    return p;
  };
  u16* wqt  = alloc((size_t)HDIM * HDIM);
  u16* wot  = alloc((size_t)HDIM * HDIM);
  u16* wkt  = alloc((size_t)HDIM * CDIM);
  u16* wvt  = alloc((size_t)HDIM * CDIM);
  u16* ehsp = alloc((size_t)BB * SKV_PAD * CDIM);
  u16* khb  = alloc((size_t)BB * HEADS * SKV_PAD * HD);
  u16* vtb  = alloc((size_t)BB * HEADS * HD * SKV_PAD);
  u16* qb   = alloc((size_t)BB * SQ * HDIM);
  u16* ao   = alloc((size_t)BB * SQ * HDIM);
  u16* hsb  = ao;  // alias: hsb dead before attention writes ao

  tcvt<<<dim3(HDIM / 32, HDIM / 32), 256, 0, stream>>>(Wq, wqt, HDIM, HDIM, 0.125f);
  tcvt<<<dim3(HDIM / 32, CDIM / 32), 256, 0, stream>>>(Wk, wkt, CDIM, HDIM, 1.0f);
  tcvt<<<dim3(HDIM / 32, CDIM / 32), 256, 0, stream>>>(Wv, wvt, CDIM, HDIM, 1.0f);
  tcvt<<<dim3(HDIM / 32, HDIM / 32), 256, 0, stream>>>(Wo, wot, HDIM, HDIM, 1.0f);
  ehs_prep<<<dim3((BB * SKV_PAD * CDIM / 4 + 255) / 256), 256, 0, stream>>>(ehs, ehsp);
  hscvt<<<dim3(2048), 256, 0, stream>>>(hs, hsb);

  // K,V projections (M = 1024 padded rows; grid 80 % 8 == 0)
  gemm_glds<1><<<dim3(80), 256, 0, stream>>>(ehsp, wkt, khb, CDIM, 10);
  gemm_glds<2><<<dim3(80), 256, 0, stream>>>(ehsp, wvt, vtb, CDIM, 10);
  // Q projection: 128x256 3-buf counted-vmcnt (grid 256*5 = 1280, % 8 == 0)
  gemm_v2<0><<<dim3(1280), 512, 0, stream>>>(hsb, wqt, qb, HDIM, 5, nullptr, nullptr);
  // attention
  attn_kernel<<<dim3(SQ / 64, BB * HEADS), 256, 0, stream>>>(qb, khb, vtb, ao);
  // output projection + bias + f32 residual
  gemm_v2<3><<<dim3(1280), 512, 0, stream>>>(ao, wot, (void*)d_out, HDIM, 5, bo, hs);
}